// Round 14
// baseline (109.975 us; speedup 1.0000x reference)
//
#include <hip/hip_runtime.h>
#include <hip/hip_bf16.h>

typedef unsigned short u16;
typedef __attribute__((ext_vector_type(8))) short short8;
typedef __attribute__((ext_vector_type(4))) float f32x4;
typedef __attribute__((ext_vector_type(16))) float f32x16;

#define MFMA32(a,b,c) __builtin_amdgcn_mfma_f32_32x32x16_bf16(a,b,c,0,0,0)

__device__ __forceinline__ unsigned pk2(float a, float b){
  float2 f = make_float2(a, b);
  __hip_bfloat162 h = __float22bfloat162_rn(f);     // v_cvt_pk_bf16_f32
  unsigned u; __builtin_memcpy(&u, &h, 4); return u;
}

__device__ __forceinline__ short8 pack8(float4 a, float4 b){
  union { unsigned u[4]; short8 s; } v;
  v.u[0] = pk2(a.x, a.y); v.u[1] = pk2(a.z, a.w);
  v.u[2] = pk2(b.x, b.y); v.u[3] = pk2(b.z, b.w);
  return v.s;
}

__device__ __forceinline__ short8 pack8v(f32x4 a, f32x4 b){
  union { unsigned u[4]; short8 s; } v;
  v.u[0] = pk2(a[0], a[1]); v.u[1] = pk2(a[2], a[3]);
  v.u[2] = pk2(b[0], b[1]); v.u[3] = pk2(b[2], b[3]);
  return v.s;
}

__device__ __forceinline__ void gload_lds16(const void* g, void* l){
  __builtin_amdgcn_global_load_lds(
      (const __attribute__((address_space(1))) unsigned int*)g,
      (__attribute__((address_space(3))) unsigned int*)l, 16, 0, 0);
}

// =============== kPrep: W1-permute (B frag chunks) + W2T + GEMM3 ==========
// blocks 0..319: w1bp 16B-slot g: c=g/1280, r=g%1280, nt=r>>7, s=(r>>6)&1,
//   l=r&63; slot holds W1[nt*32+(l&31)][c*32 + s*16 + (l>>5)*8 + j], j=0..7.
//   -> chunk c = 20KB contiguous, DMA-linear, ds_read 16B/lane conflict-free.
__global__ __launch_bounds__(256) void kprep(
    const float* __restrict__ W1, const float* __restrict__ W2,
    const float* __restrict__ feat, const float* __restrict__ W3,
    u16* __restrict__ w1bp, float* __restrict__ W2T, float* __restrict__ l3p)
{
  __shared__ float tile[32][33];
  __shared__ __attribute__((aligned(16))) float At[32*68];
  __shared__ __attribute__((aligned(16))) float Bt[32*68];
  const int bid = blockIdx.x;
  const int t = threadIdx.x;

  if (bid < 320){
    int g = bid * 256 + t;            // 0..81919
    int c = g / 1280;
    int r = g - c * 1280;
    int nt = r >> 7;
    int s = (r >> 6) & 1;
    int l = r & 63;
    int row = nt*32 + (l & 31);
    int k = c*32 + s*16 + (l >> 5)*8;
    const float4* src = (const float4*)(W1 + (size_t)row * 2048 + k);
    *(short8*)(w1bp + (size_t)g * 8) = pack8(src[0], src[1]);
  } else if (bid < 640){
    const int bb = bid - 320;
    const int tx = t & 31, ty = t >> 5;          // 32 x 8
    const int bx = bb & 31;                      // c tile (32 -> 1024)
    const int by = bb >> 5;                      // a tile (10 -> 320)
#pragma unroll
    for (int k = 0; k < 4; ++k){
      int c = bx*32 + ty + k*8;
      int a = by*32 + tx;
      tile[ty + k*8][tx] = (c < 1000) ? W2[(size_t)c*320 + a] : 0.f;
    }
    __syncthreads();
#pragma unroll
    for (int k = 0; k < 4; ++k){
      int a = by*32 + ty + k*8;
      int c = bx*32 + tx;
      W2T[(size_t)a*1024 + c] = tile[tx][ty + k*8];
    }
  } else {
    // ---- GEMM3: 64x64 C tile, K chunk 128 (4 stages of 32) ----
    const int bb = bid - 640;
    const int kg = bb & 15;
    const int cg = bb >> 4;
    const int cbase = cg * 64;
    const int tm = t >> 4, tn = t & 15;
    const int sr = t >> 2, skc = (t & 3) * 8;
    f32x4 acc4[4];
#pragma unroll
    for (int i = 0; i < 4; ++i) acc4[i] = (f32x4){0.f,0.f,0.f,0.f};

    for (int st = 0; st < 4; ++st){
      const int kbase = kg*128 + st*32;
      {
        const float4* s = (const float4*)(feat + (size_t)sr*2048 + kbase + skc);
        float4 v0 = s[0], v1 = s[1];
        At[(skc+0)*68 + sr] = v0.x; At[(skc+1)*68 + sr] = v0.y;
        At[(skc+2)*68 + sr] = v0.z; At[(skc+3)*68 + sr] = v0.w;
        At[(skc+4)*68 + sr] = v1.x; At[(skc+5)*68 + sr] = v1.y;
        At[(skc+6)*68 + sr] = v1.z; At[(skc+7)*68 + sr] = v1.w;
      }
      {
        int c = cbase + sr;
        float4 v0 = {0,0,0,0}, v1 = {0,0,0,0};
        if (c < 1000){
          const float4* s = (const float4*)(W3 + (size_t)c*2048 + kbase + skc);
          v0 = s[0]; v1 = s[1];
        }
        Bt[(skc+0)*68 + sr] = v0.x; Bt[(skc+1)*68 + sr] = v0.y;
        Bt[(skc+2)*68 + sr] = v0.z; Bt[(skc+3)*68 + sr] = v0.w;
        Bt[(skc+4)*68 + sr] = v1.x; Bt[(skc+5)*68 + sr] = v1.y;
        Bt[(skc+6)*68 + sr] = v1.z; Bt[(skc+7)*68 + sr] = v1.w;
      }
      __syncthreads();
#pragma unroll
      for (int kk = 0; kk < 32; ++kk){
        f32x4 a = *(const f32x4*)(At + kk*68 + tm*4);
        f32x4 b = *(const f32x4*)(Bt + kk*68 + tn*4);
        acc4[0] += a[0] * b;
        acc4[1] += a[1] * b;
        acc4[2] += a[2] * b;
        acc4[3] += a[3] * b;
      }
      __syncthreads();
    }
#pragma unroll
    for (int i = 0; i < 4; ++i)
      *(f32x4*)(l3p + (size_t)kg*65536 + (tm*4+i)*1024 + cbase + tn*4) = acc4[i];
  }
}

// =============== K1: GEMM1 (32x32 MFMA) + softmax + region partials =======
// grid 392 (M=32), block 64 = ONE wave; no barriers. Both A (f32, swizzled
// via pre-swizzled global src) and B (bf16, linear) DMA'd via global_load_lds
// into 3-deep LDS buffers. Pacing: s_waitcnt vmcnt(48) retires exactly
// DMA(k); DMA(k+1), DMA(k+2) stay in flight (~2 iters slack > HBM latency).
__global__ __launch_bounds__(64, 1) void k1_main(
    const float* __restrict__ am, const u16* __restrict__ w1bp,
    float* __restrict__ partial)
{
  __shared__ __attribute__((aligned(16))) u16  Bl[3][10240];   // 3 x 20 KB
  __shared__ __attribute__((aligned(16))) float Al[3][1024];   // 3 x 4 KB

  const int l = threadIdx.x;
  const int blk = blockIdx.x;
  const int rA = l & 31, hA = l >> 5;

  f32x16 acc[10];
#pragma unroll
  for (int nt = 0; nt < 10; ++nt)
#pragma unroll
    for (int r = 0; r < 16; ++r) acc[nt][r] = 0.f;

  // DMA sources (per-lane); LDS dests are wave-uniform (rule 21 clean)
  const char*  bsrc = (const char*)w1bp + (size_t)l*16;
  const float* asrc = am + (size_t)(blk*32 + (l>>3))*2048
                         + ((l & 7) ^ ((l >> 3) & 7))*4;   // pre-swizzled src

  // A ds_read byte offsets: slot S = s*4 + hA*2 + j, stored at S^(rA&7)
  const int a00 = rA*128 + (((0 + hA*2 + 0) ^ (rA & 7))*16);
  const int a01 = rA*128 + (((0 + hA*2 + 1) ^ (rA & 7))*16);
  const int a10 = rA*128 + (((4 + hA*2 + 0) ^ (rA & 7))*16);
  const int a11 = rA*128 + (((4 + hA*2 + 1) ^ (rA & 7))*16);
  const int bofs = l*16;

#define DMAC(KC, BW)                                                    \
  { const char* bp = bsrc + (size_t)(KC)*20480;                         \
    char* bd = (char*)&Bl[BW][0];                                       \
    _Pragma("unroll")                                                   \
    for (int i = 0; i < 20; ++i)                                        \
      gload_lds16(bp + i*1024, bd + i*1024);                            \
    const float* ap = asrc + (size_t)(KC)*32;                           \
    char* ad = (char*)&Al[BW][0];                                       \
    _Pragma("unroll")                                                   \
    for (int q = 0; q < 4; ++q)                                         \
      gload_lds16(ap + q*16384, ad + q*1024); }

#define CMP(BR)                                                         \
  { const char* ab = (const char*)&Al[BR][0];                           \
    f32x4 lo0 = *(const f32x4*)(ab + a00);                              \
    f32x4 hi0 = *(const f32x4*)(ab + a01);                              \
    f32x4 lo1 = *(const f32x4*)(ab + a10);                              \
    f32x4 hi1 = *(const f32x4*)(ab + a11);                              \
    short8 af0 = pack8v(lo0, hi0);                                      \
    short8 af1 = pack8v(lo1, hi1);                                      \
    const char* bbuf = (const char*)&Bl[BR][0];                         \
    _Pragma("unroll")                                                   \
    for (int nt = 0; nt < 10; ++nt){                                    \
      short8 b0 = *(const short8*)(bbuf + (nt*2+0)*1024 + bofs);        \
      short8 b1 = *(const short8*)(bbuf + (nt*2+1)*1024 + bofs);        \
      acc[nt] = MFMA32(af0, b0, acc[nt]);                               \
      acc[nt] = MFMA32(af1, b1, acc[nt]); } }

#define STEP(K, BR, BW)                                                 \
  { int kc = (K) + 2; kc = kc > 63 ? 63 : kc;                           \
    DMAC(kc, BW);                                                       \
    asm volatile("s_waitcnt vmcnt(48)" ::: "memory");                   \
    CMP(BR); }

  // ---------------- prologue: DMA(0), DMA(1) ----------------
  DMAC(0, 0);
  DMAC(1, 1);

  // ---------------- 64 chunks: 21 triples + tail ----------------
#pragma unroll 1
  for (int k3 = 0; k3 < 21; ++k3){
    const int K = 3*k3;
    STEP(K+0, 0, 2);
    STEP(K+1, 1, 0);
    STEP(K+2, 2, 1);
  }
  STEP(63, 0, 2);
  asm volatile("s_waitcnt vmcnt(0) lgkmcnt(0)" ::: "memory");

#undef STEP
#undef CMP
#undef DMAC

  // ---- epilogue: in-wave softmax over 320 cols ----
  // C/D: col = nt*32 + (l&31); row = (r&3) + 8*(r>>2) + 4*hA
  float rmx[16];
#pragma unroll
  for (int r = 0; r < 16; ++r){
    float x = acc[0][r];
#pragma unroll
    for (int nt = 1; nt < 10; ++nt) x = fmaxf(x, acc[nt][r]);
    x = fmaxf(x, __shfl_xor(x, 1));
    x = fmaxf(x, __shfl_xor(x, 2));
    x = fmaxf(x, __shfl_xor(x, 4));
    x = fmaxf(x, __shfl_xor(x, 8));
    x = fmaxf(x, __shfl_xor(x, 16));
    rmx[r] = x;
  }
#pragma unroll
  for (int r = 0; r < 16; ++r){
    float s = 0.f;
#pragma unroll
    for (int nt = 0; nt < 10; ++nt){
      float e = __expf(acc[nt][r] - rmx[r]);
      acc[nt][r] = e; s += e;
    }
    s += __shfl_xor(s, 1);
    s += __shfl_xor(s, 2);
    s += __shfl_xor(s, 4);
    s += __shfl_xor(s, 8);
    s += __shfl_xor(s, 16);
    rmx[r] = 1.f / s;
  }
  const int n0 = blk * 32;
  const int thr = 196 * (n0/196 + 1) - n0;    // rows-in-block < thr -> seg0
  float s0v[10], s1v[10];
#pragma unroll
  for (int nt = 0; nt < 10; ++nt){
    float s0 = 0.f, s1 = 0.f;
#pragma unroll
    for (int r = 0; r < 16; ++r){
      int row = (r & 3) + 8*(r >> 2) + 4*hA;
      float v = acc[nt][r] * rmx[r];
      if (row < thr) s0 += v; else s1 += v;
    }
    s0 += __shfl_xor(s0, 32);
    s1 += __shfl_xor(s1, 32);
    s0v[nt] = s0; s1v[nt] = s1;
  }
  if (l < 32){
#pragma unroll
    for (int nt = 0; nt < 10; ++nt){
      partial[blk*640 +       nt*32 + l] = s0v[nt];
      partial[blk*640 + 320 + nt*32 + l] = s1v[nt];
    }
  }
}

// =============== K2c: reduce partials + attr_dis@W2T + both softmax =======
__global__ __launch_bounds__(256) void k2c_final(
    const float* __restrict__ partialp, const float* __restrict__ W2T,
    const float* __restrict__ l3p, float* __restrict__ outp,
    float* __restrict__ out_ad)
{
  __shared__ __attribute__((aligned(16))) float sad[320];
  __shared__ float redA[4], redB[4];
  const int b = blockIdx.x, t = threadIdx.x;
  const int w = t >> 6, l = t & 63;
  const int lo = (196*b) >> 5, hi = (196*b + 195) >> 5;
  for (int i = t; i < 320; i += 256){
    float s = 0.f;
    for (int blk = lo; blk <= hi; ++blk){
      int seg = b - (blk*32)/196;
      if (seg >= 0 && seg < 2) s += partialp[blk*640 + seg*320 + i];
    }
    s *= (1.f / 320.f);
    sad[i] = s;
    out_ad[b*320 + i] = s;
  }
  __syncthreads();
  const int c0 = t * 4;
  f32x4 s2v = {0.f,0.f,0.f,0.f};
  const float4* a4 = (const float4*)sad;
#pragma unroll 4
  for (int i = 0; i < 80; ++i){
    float4 sv = a4[i];
    f32x4 w0 = *(const f32x4*)(W2T + (size_t)(4*i  )*1024 + c0);
    f32x4 w1 = *(const f32x4*)(W2T + (size_t)(4*i+1)*1024 + c0);
    f32x4 w2 = *(const f32x4*)(W2T + (size_t)(4*i+2)*1024 + c0);
    f32x4 w3 = *(const f32x4*)(W2T + (size_t)(4*i+3)*1024 + c0);
    s2v += sv.x*w0 + sv.y*w1 + sv.z*w2 + sv.w*w3;
  }
  f32x4 s3v = {0.f,0.f,0.f,0.f};
#pragma unroll
  for (int kg = 0; kg < 16; ++kg)
    s3v += *(const f32x4*)(l3p + (size_t)kg*65536 + b*1024 + c0);
  float l2a[4], l3a[4];
#pragma unroll
  for (int jj = 0; jj < 4; ++jj){
    bool valid = (c0 + jj) < 1000;
    l2a[jj] = valid ? s2v[jj] : -3.4e38f;
    l3a[jj] = valid ? s3v[jj] : -3.4e38f;
  }
  float m2 = fmaxf(fmaxf(l2a[0],l2a[1]), fmaxf(l2a[2],l2a[3]));
  float m3 = fmaxf(fmaxf(l3a[0],l3a[1]), fmaxf(l3a[2],l3a[3]));
#pragma unroll
  for (int off = 32; off > 0; off >>= 1){
    m2 = fmaxf(m2, __shfl_xor(m2, off));
    m3 = fmaxf(m3, __shfl_xor(m3, off));
  }
  if (l == 0){ redA[w] = m2; redB[w] = m3; }
  __syncthreads();
  m2 = fmaxf(fmaxf(redA[0],redA[1]), fmaxf(redA[2],redA[3]));
  m3 = fmaxf(fmaxf(redB[0],redB[1]), fmaxf(redB[2],redB[3]));
  __syncthreads();
  float e2[4], e3[4], s2 = 0.f, s3 = 0.f;
#pragma unroll
  for (int jj = 0; jj < 4; ++jj){
    bool valid = (c0 + jj) < 1000;
    e2[jj] = valid ? __expf(l2a[jj] - m2) : 0.f;
    e3[jj] = valid ? __expf(l3a[jj] - m3) : 0.f;
    s2 += e2[jj]; s3 += e3[jj];
  }
#pragma unroll
  for (int off = 32; off > 0; off >>= 1){
    s2 += __shfl_xor(s2, off);
    s3 += __shfl_xor(s3, off);
  }
  if (l == 0){ redA[w] = s2; redB[w] = s3; }
  __syncthreads();
  s2 = redA[0] + redA[1] + redA[2] + redA[3];
  s3 = redB[0] + redB[1] + redB[2] + redB[3];
  float i2 = 1.f / s2, i3 = 1.f / s3;
#pragma unroll
  for (int jj = 0; jj < 4; ++jj){
    int c = c0 + jj;
    if (c < 1000) outp[b*1000 + c] = 0.5f * (e2[jj]*i2 + e3[jj]*i3);
  }
}

extern "C" void kernel_launch(void* const* d_in, const int* in_sizes, int n_in,
                              void* d_out, int out_size, void* d_ws, size_t ws_size,
                              hipStream_t stream)
{
  const float* attr_map = (const float*)d_in[0];
  const float* features = (const float*)d_in[1];
  const float* W1 = (const float*)d_in[2];
  const float* W2 = (const float*)d_in[3];
  const float* W3 = (const float*)d_in[4];
  float* outp = (float*)d_out;

  char* ws = (char*)d_ws;
  u16*   w1bp    = (u16*)ws;                       // 1,310,720 B
  float* W2T     = (float*)(ws + 1310720);         // 1,310,720 B
  float* partial = (float*)(ws + 2621440);         // 1,003,520 B
  float* l3p     = (float*)(ws + 3624960);         // 4,194,304 B (total 7.8 MB)

  kprep    <<<896, 256, 0, stream>>>(W1, W2, features, W3, w1bp, W2T, l3p);
  k1_main  <<<392, 64, 0, stream>>>(attr_map, w1bp, partial);
  k2c_final<<<64, 256, 0, stream>>>(partial, W2T, l3p, outp, outp + 64000);
}

// Round 15
// 91.605 us; speedup vs baseline: 1.2005x; 1.2005x over previous
//
#include <hip/hip_runtime.h>
#include <hip/hip_bf16.h>

typedef unsigned short u16;
typedef __attribute__((ext_vector_type(8))) short short8;
typedef __attribute__((ext_vector_type(4))) float f32x4;
typedef __attribute__((ext_vector_type(16))) float f32x16;

#define MFMA32(a,b,c) __builtin_amdgcn_mfma_f32_32x32x16_bf16(a,b,c,0,0,0)

__device__ __forceinline__ unsigned pk2(float a, float b){
  float2 f = make_float2(a, b);
  __hip_bfloat162 h = __float22bfloat162_rn(f);     // v_cvt_pk_bf16_f32
  unsigned u; __builtin_memcpy(&u, &h, 4); return u;
}

__device__ __forceinline__ short8 pack8(float4 a, float4 b){
  union { unsigned u[4]; short8 s; } v;
  v.u[0] = pk2(a.x, a.y); v.u[1] = pk2(a.z, a.w);
  v.u[2] = pk2(b.x, b.y); v.u[3] = pk2(b.z, b.w);
  return v.s;
}

__device__ __forceinline__ short8 pack8v(f32x4 a, f32x4 b){
  union { unsigned u[4]; short8 s; } v;
  v.u[0] = pk2(a[0], a[1]); v.u[1] = pk2(a[2], a[3]);
  v.u[2] = pk2(b[0], b[1]); v.u[3] = pk2(b[2], b[3]);
  return v.s;
}

__device__ __forceinline__ void gload_lds16(const void* g, void* l){
  __builtin_amdgcn_global_load_lds(
      (const __attribute__((address_space(1))) unsigned int*)g,
      (__attribute__((address_space(3))) unsigned int*)l, 16, 0, 0);
}

// =============== kPrep: W1-permute (B frag chunks) + W2T + GEMM3 ==========
// blocks 0..319: w1bp 16B-slot g: c=g/1280, r=g%1280, nt=r>>7, s=(r>>6)&1,
//   l=r&63; slot holds W1[nt*32+(l&31)][c*32 + s*16 + (l>>5)*8 + j], j=0..7.
//   -> chunk c = 20KB contiguous, DMA-linear, ds_read 16B/lane conflict-free.
__global__ __launch_bounds__(256) void kprep(
    const float* __restrict__ W1, const float* __restrict__ W2,
    const float* __restrict__ feat, const float* __restrict__ W3,
    u16* __restrict__ w1bp, float* __restrict__ W2T, float* __restrict__ l3p)
{
  __shared__ float tile[32][33];
  __shared__ __attribute__((aligned(16))) float At[32*68];
  __shared__ __attribute__((aligned(16))) float Bt[32*68];
  const int bid = blockIdx.x;
  const int t = threadIdx.x;

  if (bid < 320){
    int g = bid * 256 + t;            // 0..81919
    int c = g / 1280;
    int r = g - c * 1280;
    int nt = r >> 7;
    int s = (r >> 6) & 1;
    int l = r & 63;
    int row = nt*32 + (l & 31);
    int k = c*32 + s*16 + (l >> 5)*8;
    const float4* src = (const float4*)(W1 + (size_t)row * 2048 + k);
    *(short8*)(w1bp + (size_t)g * 8) = pack8(src[0], src[1]);
  } else if (bid < 640){
    const int bb = bid - 320;
    const int tx = t & 31, ty = t >> 5;          // 32 x 8
    const int bx = bb & 31;                      // c tile (32 -> 1024)
    const int by = bb >> 5;                      // a tile (10 -> 320)
#pragma unroll
    for (int k = 0; k < 4; ++k){
      int c = bx*32 + ty + k*8;
      int a = by*32 + tx;
      tile[ty + k*8][tx] = (c < 1000) ? W2[(size_t)c*320 + a] : 0.f;
    }
    __syncthreads();
#pragma unroll
    for (int k = 0; k < 4; ++k){
      int a = by*32 + ty + k*8;
      int c = bx*32 + tx;
      W2T[(size_t)a*1024 + c] = tile[tx][ty + k*8];
    }
  } else {
    // ---- GEMM3: 64x64 C tile, K chunk 128 (4 stages of 32) ----
    const int bb = bid - 640;
    const int kg = bb & 15;
    const int cg = bb >> 4;
    const int cbase = cg * 64;
    const int tm = t >> 4, tn = t & 15;
    const int sr = t >> 2, skc = (t & 3) * 8;
    f32x4 acc4[4];
#pragma unroll
    for (int i = 0; i < 4; ++i) acc4[i] = (f32x4){0.f,0.f,0.f,0.f};

    for (int st = 0; st < 4; ++st){
      const int kbase = kg*128 + st*32;
      {
        const float4* s = (const float4*)(feat + (size_t)sr*2048 + kbase + skc);
        float4 v0 = s[0], v1 = s[1];
        At[(skc+0)*68 + sr] = v0.x; At[(skc+1)*68 + sr] = v0.y;
        At[(skc+2)*68 + sr] = v0.z; At[(skc+3)*68 + sr] = v0.w;
        At[(skc+4)*68 + sr] = v1.x; At[(skc+5)*68 + sr] = v1.y;
        At[(skc+6)*68 + sr] = v1.z; At[(skc+7)*68 + sr] = v1.w;
      }
      {
        int c = cbase + sr;
        float4 v0 = {0,0,0,0}, v1 = {0,0,0,0};
        if (c < 1000){
          const float4* s = (const float4*)(W3 + (size_t)c*2048 + kbase + skc);
          v0 = s[0]; v1 = s[1];
        }
        Bt[(skc+0)*68 + sr] = v0.x; Bt[(skc+1)*68 + sr] = v0.y;
        Bt[(skc+2)*68 + sr] = v0.z; Bt[(skc+3)*68 + sr] = v0.w;
        Bt[(skc+4)*68 + sr] = v1.x; Bt[(skc+5)*68 + sr] = v1.y;
        Bt[(skc+6)*68 + sr] = v1.z; Bt[(skc+7)*68 + sr] = v1.w;
      }
      __syncthreads();
#pragma unroll
      for (int kk = 0; kk < 32; ++kk){
        f32x4 a = *(const f32x4*)(At + kk*68 + tm*4);
        f32x4 b = *(const f32x4*)(Bt + kk*68 + tn*4);
        acc4[0] += a[0] * b;
        acc4[1] += a[1] * b;
        acc4[2] += a[2] * b;
        acc4[3] += a[3] * b;
      }
      __syncthreads();
    }
#pragma unroll
    for (int i = 0; i < 4; ++i)
      *(f32x4*)(l3p + (size_t)kg*65536 + (tm*4+i)*1024 + cbase + tn*4) = acc4[i];
  }
}

// =============== K1: GEMM1 (32x32 MFMA) + softmax + region partials =======
// grid 392 (M=32), block 256 = 4 waves. Wave w: nh=w&1 (nt 5), kf=w>>1 (k-half).
// All staging via global_load_lds (3-deep), counted vmcnt(6)+lgkm(0)+barrier.
// acc = 80 VGPR/wave -> 2 blocks/CU (8 waves). K-halves reduced via LDS at end.
__global__ __launch_bounds__(256, 2) void k1_main(
    const float* __restrict__ am, const u16* __restrict__ w1bp,
    float* __restrict__ partial)
{
  __shared__ __attribute__((aligned(16))) u16   Bl[3][10240];  // 3 x 20 KB
  __shared__ __attribute__((aligned(16))) float Al[3][1024];   // 3 x 4 KB
  __shared__ float redM[32][2];
  __shared__ float redS[32][2];

  const int t = threadIdx.x;
  const int wv = t >> 6, l = t & 63;
  const int nh = wv & 1, kf = wv >> 1;
  const int rA = l & 31, hA = l >> 5;
  const int blk = blockIdx.x;

  f32x16 acc[5];
#pragma unroll
  for (int j = 0; j < 5; ++j)
#pragma unroll
    for (int r = 0; r < 16; ++r) acc[j][r] = 0.f;

  // DMA sources (per-lane addr; LDS dests wave-uniform)
  const char* bsrcb = (const char*)w1bp + (size_t)(wv*5)*1024 + (size_t)l*16;
  const char* asrcb = (const char*)(am + (size_t)(blk*32 + wv*8 + (l>>3))*2048)
                      + (size_t)(((l&7) ^ ((l>>3)&7) ^ (wv&3)) * 16);

  // A ds_read offsets: row rA, 16B-slot s stored at s ^ (rA&7) ^ ((rA>>3)&3)
  const int sw = (rA & 7) ^ ((rA >> 3) & 3);
  const int aoff0 = rA*128 + (((kf*4 + hA*2 + 0) ^ sw) * 16);
  const int aoff1 = rA*128 + (((kf*4 + hA*2 + 1) ^ sw) * 16);
  // B frag byte offset for nt = nh*5 + j: ((nt*2+kf)*64 + l)*16
  const int bq = (nh*10 + kf)*1024 + l*16;

#define DMAC(KC, BUF)                                                   \
  { _Pragma("unroll")                                                   \
    for (int i = 0; i < 5; ++i)                                         \
      gload_lds16(bsrcb + (size_t)(KC)*20480 + i*1024,                  \
                  (char*)&Bl[BUF][0] + (wv*5 + i)*1024);                \
    gload_lds16(asrcb + (size_t)(KC)*128, (char*)&Al[BUF][0] + wv*1024); }

#define CMP(BUF)                                                        \
  { const char* ab = (const char*)&Al[BUF][0];                          \
    f32x4 lo = *(const f32x4*)(ab + aoff0);                             \
    f32x4 hi = *(const f32x4*)(ab + aoff1);                             \
    short8 af = pack8v(lo, hi);                                         \
    const char* bb2 = (const char*)&Bl[BUF][0] + bq;                    \
    _Pragma("unroll")                                                   \
    for (int j = 0; j < 5; ++j){                                        \
      short8 bf = *(const short8*)(bb2 + j*2048);                       \
      acc[j] = MFMA32(af, bf, acc[j]);                                  \
    } }

#define WB6() asm volatile("s_waitcnt vmcnt(6) lgkmcnt(0)\n\ts_barrier" ::: "memory")

  // ---------------- prologue: DMA(0)->buf0, DMA(1)->buf1 ----------------
  DMAC(0, 0);
  DMAC(1, 1);

  // ---------------- K-loop: 64 chunks (BK=32) ----------------
#pragma unroll 1
  for (int k3 = 0; k3 < 20; ++k3){
    const int kb = 3*k3;
    WB6(); DMAC(kb+2, 2); CMP(0);
    WB6(); DMAC(kb+3, 0); CMP(1);
    WB6(); DMAC(kb+4, 1); CMP(2);
  }
  WB6(); DMAC(62, 2); CMP(0);                       // k=60
  WB6(); DMAC(63, 0); CMP(1);                       // k=61
  WB6(); CMP(2);                                    // k=62 (63 in flight)
  asm volatile("s_waitcnt vmcnt(0) lgkmcnt(0)\n\ts_barrier" ::: "memory");
  CMP(0);                                           // k=63

#undef WB6
#undef CMP
#undef DMAC

  // ---------------- k-half reduction via LDS (reuse Bl) ----------------
  __syncthreads();
  float* redc = (float*)&Bl[0][0];                  // 40 KB needed, 60 avail
  if (kf == 1){
#pragma unroll
    for (int j = 0; j < 5; ++j)
#pragma unroll
      for (int r = 0; r < 16; ++r)
        redc[(size_t)((nh*5 + j)*16 + r)*64 + l] = acc[j][r];
  }
  __syncthreads();
  if (kf == 0){
#pragma unroll
    for (int j = 0; j < 5; ++j)
#pragma unroll
      for (int r = 0; r < 16; ++r)
        acc[j][r] += redc[(size_t)((nh*5 + j)*16 + r)*64 + l];
  }

  // ---- epilogue (kf==0 waves): softmax over 320 cols ----
  // C/D: col = (nh*5+j)*32 + (l&31); row = (r&3) + 8*(r>>2) + 4*hA
  float rmx[16];
  if (kf == 0){
#pragma unroll
    for (int r = 0; r < 16; ++r){
      float x = acc[0][r];
#pragma unroll
      for (int j = 1; j < 5; ++j) x = fmaxf(x, acc[j][r]);
      x = fmaxf(x, __shfl_xor(x, 1));
      x = fmaxf(x, __shfl_xor(x, 2));
      x = fmaxf(x, __shfl_xor(x, 4));
      x = fmaxf(x, __shfl_xor(x, 8));
      x = fmaxf(x, __shfl_xor(x, 16));
      rmx[r] = x;
    }
    if ((l & 31) == 0){
#pragma unroll
      for (int r = 0; r < 16; ++r)
        redM[(r&3) + 8*(r>>2) + 4*hA][nh] = rmx[r];
    }
  }
  __syncthreads();
  if (kf == 0){
#pragma unroll
    for (int r = 0; r < 16; ++r){
      int row = (r&3) + 8*(r>>2) + 4*hA;
      float m = fmaxf(redM[row][0], redM[row][1]);
      float s = 0.f;
#pragma unroll
      for (int j = 0; j < 5; ++j){
        float e = __expf(acc[j][r] - m);
        acc[j][r] = e; s += e;
      }
      s += __shfl_xor(s, 1);
      s += __shfl_xor(s, 2);
      s += __shfl_xor(s, 4);
      s += __shfl_xor(s, 8);
      s += __shfl_xor(s, 16);
      rmx[r] = s;
    }
    if ((l & 31) == 0){
#pragma unroll
      for (int r = 0; r < 16; ++r)
        redS[(r&3) + 8*(r>>2) + 4*hA][nh] = rmx[r];
    }
  }
  __syncthreads();
  if (kf == 0){
    const int n0 = blk * 32;
    const int thr = 196 * (n0/196 + 1) - n0;        // rows < thr -> seg0
#pragma unroll
    for (int r = 0; r < 16; ++r){
      int row = (r&3) + 8*(r>>2) + 4*hA;
      rmx[r] = 1.f / (redS[row][0] + redS[row][1]);
    }
#pragma unroll
    for (int j = 0; j < 5; ++j){
      float s0 = 0.f, s1 = 0.f;
#pragma unroll
      for (int r = 0; r < 16; ++r){
        int row = (r&3) + 8*(r>>2) + 4*hA;
        float v = acc[j][r] * rmx[r];
        if (row < thr) s0 += v; else s1 += v;
      }
      s0 += __shfl_xor(s0, 32);
      s1 += __shfl_xor(s1, 32);
      if (l < 32){
        partial[blk*640 +       (nh*5 + j)*32 + l] = s0;
        partial[blk*640 + 320 + (nh*5 + j)*32 + l] = s1;
      }
    }
  }
}

// =============== K2c: reduce partials + attr_dis@W2T + both softmax =======
__global__ __launch_bounds__(256) void k2c_final(
    const float* __restrict__ partialp, const float* __restrict__ W2T,
    const float* __restrict__ l3p, float* __restrict__ outp,
    float* __restrict__ out_ad)
{
  __shared__ __attribute__((aligned(16))) float sad[320];
  __shared__ float redA[4], redB[4];
  const int b = blockIdx.x, t = threadIdx.x;
  const int w = t >> 6, l = t & 63;
  const int lo = (196*b) >> 5, hi = (196*b + 195) >> 5;
  for (int i = t; i < 320; i += 256){
    float s = 0.f;
    for (int blk = lo; blk <= hi; ++blk){
      int seg = b - (blk*32)/196;
      if (seg >= 0 && seg < 2) s += partialp[blk*640 + seg*320 + i];
    }
    s *= (1.f / 320.f);
    sad[i] = s;
    out_ad[b*320 + i] = s;
  }
  __syncthreads();
  const int c0 = t * 4;
  f32x4 s2v = {0.f,0.f,0.f,0.f};
  const float4* a4 = (const float4*)sad;
#pragma unroll 4
  for (int i = 0; i < 80; ++i){
    float4 sv = a4[i];
    f32x4 w0 = *(const f32x4*)(W2T + (size_t)(4*i  )*1024 + c0);
    f32x4 w1 = *(const f32x4*)(W2T + (size_t)(4*i+1)*1024 + c0);
    f32x4 w2 = *(const f32x4*)(W2T + (size_t)(4*i+2)*1024 + c0);
    f32x4 w3 = *(const f32x4*)(W2T + (size_t)(4*i+3)*1024 + c0);
    s2v += sv.x*w0 + sv.y*w1 + sv.z*w2 + sv.w*w3;
  }
  f32x4 s3v = {0.f,0.f,0.f,0.f};
#pragma unroll
  for (int kg = 0; kg < 16; ++kg)
    s3v += *(const f32x4*)(l3p + (size_t)kg*65536 + b*1024 + c0);
  float l2a[4], l3a[4];
#pragma unroll
  for (int jj = 0; jj < 4; ++jj){
    bool valid = (c0 + jj) < 1000;
    l2a[jj] = valid ? s2v[jj] : -3.4e38f;
    l3a[jj] = valid ? s3v[jj] : -3.4e38f;
  }
  float m2 = fmaxf(fmaxf(l2a[0],l2a[1]), fmaxf(l2a[2],l2a[3]));
  float m3 = fmaxf(fmaxf(l3a[0],l3a[1]), fmaxf(l3a[2],l3a[3]));
#pragma unroll
  for (int off = 32; off > 0; off >>= 1){
    m2 = fmaxf(m2, __shfl_xor(m2, off));
    m3 = fmaxf(m3, __shfl_xor(m3, off));
  }
  if (l == 0){ redA[w] = m2; redB[w] = m3; }
  __syncthreads();
  m2 = fmaxf(fmaxf(redA[0],redA[1]), fmaxf(redA[2],redA[3]));
  m3 = fmaxf(fmaxf(redB[0],redB[1]), fmaxf(redB[2],redB[3]));
  __syncthreads();
  float e2[4], e3[4], s2 = 0.f, s3 = 0.f;
#pragma unroll
  for (int jj = 0; jj < 4; ++jj){
    bool valid = (c0 + jj) < 1000;
    e2[jj] = valid ? __expf(l2a[jj] - m2) : 0.f;
    e3[jj] = valid ? __expf(l3a[jj] - m3) : 0.f;
    s2 += e2[jj]; s3 += e3[jj];
  }
#pragma unroll
  for (int off = 32; off > 0; off >>= 1){
    s2 += __shfl_xor(s2, off);
    s3 += __shfl_xor(s3, off);
  }
  if (l == 0){ redA[w] = s2; redB[w] = s3; }
  __syncthreads();
  s2 = redA[0] + redA[1] + redA[2] + redA[3];
  s3 = redB[0] + redB[1] + redB[2] + redB[3];
  float i2 = 1.f / s2, i3 = 1.f / s3;
#pragma unroll
  for (int jj = 0; jj < 4; ++jj){
    int c = c0 + jj;
    if (c < 1000) outp[b*1000 + c] = 0.5f * (e2[jj]*i2 + e3[jj]*i3);
  }
}

extern "C" void kernel_launch(void* const* d_in, const int* in_sizes, int n_in,
                              void* d_out, int out_size, void* d_ws, size_t ws_size,
                              hipStream_t stream)
{
  const float* attr_map = (const float*)d_in[0];
  const float* features = (const float*)d_in[1];
  const float* W1 = (const float*)d_in[2];
  const float* W2 = (const float*)d_in[3];
  const float* W3 = (const float*)d_in[4];
  float* outp = (float*)d_out;

  char* ws = (char*)d_ws;
  u16*   w1bp    = (u16*)ws;                       // 1,310,720 B
  float* W2T     = (float*)(ws + 1310720);         // 1,310,720 B
  float* partial = (float*)(ws + 2621440);         // 1,003,520 B
  float* l3p     = (float*)(ws + 3624960);         // 4,194,304 B (total 7.8 MB)

  kprep    <<<896, 256, 0, stream>>>(W1, W2, features, W3, w1bp, W2T, l3p);
  k1_main  <<<392, 256, 0, stream>>>(attr_map, w1bp, partial);
  k2c_final<<<64, 256, 0, stream>>>(partial, W2T, l3p, outp, outp + 64000);
}